// Round 1
// baseline (80.959 us; speedup 1.0000x reference)
//
#include <hip/hip_runtime.h>
#include <math.h>

#define BATCH 8
#define H 256
#define W 256
#define NPIX (BATCH * H * W)
#define COLS 8                    // columns per strip
#define STRIPS (W / COLS)         // 32 strips per image
#define NBLKA (BATCH * STRIPS)    // 256 blocks, 1024 threads each

__device__ __forceinline__ float bce_logits(float p, float t) {
    return fmaxf(p, 0.0f) - p * t + log1pf(expf(-fabsf(p)));
}

// Fused: per-block redundant row-mask build (whole image, ballot) -> row EDT for
// this block's 8-column strip (LDS) -> column envelope (prologue + exact
// early-exit tail) -> fused BCE -> per-block partials. No global d16 round trip.
__global__ void __launch_bounds__(1024) fused_edt_bce(
        const float* __restrict__ target, const float* __restrict__ pred,
        float* __restrict__ pmx, float* __restrict__ psb, float* __restrict__ psdb) {
    __shared__ unsigned long long mlds[4][H];       // chunk-major zero-masks, 8 KB
    __shared__ unsigned short dtile[H][COLS + 2];   // 20 B row stride (bank spread), 5 KB
    __shared__ float red[3][16];

    const int tid = threadIdx.x;
    const int wv = tid >> 6, l = tid & 63;
    const int b     = blockIdx.x >> 5;              // image
    const int strip = blockIdx.x & 31;              // 8-column strip
    const int c0 = strip << 3;

    // Column-pass identity: lane-local column + two owned rows.
    const int cc = tid & 7;                         // column within strip
    const int tg = tid >> 3;                        // 0..127
    const int i0 = tg << 1;                         // rows i0, i0+1
    const int gc = c0 + cc;

    // pred loads issued first; consumed only in the epilogue (latency hidden
    // under the mask phase).
    const size_t po = ((size_t)(b * H + i0)) * W + gc;
    const float p0 = pred[po], p1 = pred[po + W];

    // ---- Phase 1: zero-masks for ALL 256 rows of image b (4 x 64b per row).
    // Wave wv handles pair ids q = wv*64+i: row = q>>2, chunk = q&3 ->
    // each wave streams 16 contiguous rows, fully coalesced.
    const float* img = target + (size_t)b * (H * W);
    #pragma unroll 16
    for (int i = 0; i < 64; ++i) {
        const int q   = (wv << 6) + i;
        const int row = q >> 2, ch = q & 3;
        const float t = img[row * W + (ch << 6) + l];
        const unsigned long long m = __ballot(t == 0.0f);
        if (l == 0) mlds[ch][row] = m;
    }
    __syncthreads();

    // ---- Phase 2: row EDT for our strip (256 rows x 8 cols), 2 px/thread.
    #pragma unroll
    for (int r2 = 0; r2 < 2; ++r2) {
        const int p   = tid + (r2 << 10);
        const int row = p >> 3;
        const int pc  = c0 + (p & 7);
        const unsigned long long mw[4] =
            {mlds[0][row], mlds[1][row], mlds[2][row], mlds[3][row]};
        int best = 1 << 20;
        #pragma unroll
        for (int w = 0; w < 4; ++w) {
            const int rel = pc - (w << 6);
            const unsigned long long m = mw[w];
            unsigned long long mlo = (rel < 0)  ? 0ull
                                   : (rel >= 63) ? m : (m & ((2ull << rel) - 1ull));
            unsigned long long mhi = (rel <= 0) ? m
                                   : (rel > 63)  ? 0ull : (m & (~0ull << rel));
            if (mlo) best = min(best, rel - (63 - __builtin_clzll(mlo)));
            if (mhi) best = min(best, __builtin_ctzll(mhi) - rel);
        }
        dtile[row][p & 7] = (best > 255) ? (unsigned short)10000
                                         : (unsigned short)best;   // INF per ref
    }
    __syncthreads();

    // ---- Phase 3: column envelope (identical math to previous K2, LDS reads).
    float acc0 = 3.0e38f, acc1 = 3.0e38f;
    const int P = 10;
    #pragma unroll
    for (int s = 0; s < P; ++s) {
        const int kd = i0 + 1 - s;
        const int ku = i0 + 2 + s;
        float dd = (float)dtile[max(kd, 0)][cc];
        float du = (float)dtile[min(ku, 255)][cc];
        float gd = dd * dd, gu = du * du;             // exact squares
        if (kd < 0)   gd = 3.0e38f;
        if (ku > 255) gu = 3.0e38f;
        const float ed0 = (float)(s - 1), ed1 = (float)s;
        const float eu0 = (float)(s + 2), eu1 = (float)(s + 1);
        acc0 = fminf(acc0, fminf(fmaf(ed0, ed0, gd), fmaf(eu0, eu0, gu)));
        acc1 = fminf(acc1, fminf(fmaf(ed1, ed1, gd), fmaf(eu1, eu1, gu)));
    }
    // Exact early-exit two-pointer tail (rarely runs on this data).
    int kd = i0 + 1 - P, ku = i0 + 2 + P;
    float fd0 = (float)(i0 - kd);
    float fu0 = (float)(ku - i0);
    for (;;) {
        float maxacc = fmaxf(acc0, acc1);
        float dn = (float)(i0 - kd);
        float up = (float)(ku - (i0 + 1));
        bool alive = (kd >= 0 && dn * dn <= maxacc) || (ku <= 255 && up * up <= maxacc);
        if (!__any(alive)) break;
        if (kd >= 0) {
            float dv = (float)dtile[kd][cc];
            float g = dv * dv;
            acc0 = fminf(acc0, fmaf(fd0, fd0, g));
            float fd1 = fd0 + 1.0f;
            acc1 = fminf(acc1, fmaf(fd1, fd1, g));
        }
        if (ku <= 255) {
            float dv = (float)dtile[ku][cc];
            float g = dv * dv;
            float fu1 = fu0 - 1.0f;
            acc0 = fminf(acc0, fmaf(fu0, fu0, g));
            acc1 = fminf(acc1, fmaf(fu1, fu1, g));
        }
        --kd; ++ku; fd0 += 1.0f; fu0 += 1.0f;
    }

    // ---- Epilogue: fused BCE (t derived from acc: d2==0 <=> target==0).
    float t0 = (acc0 == 0.0f) ? 0.0f : 1.0f;
    float t1 = (acc1 == 0.0f) ? 0.0f : 1.0f;
    float mx = fmaxf(acc0, acc1);
    float b0 = bce_logits(p0, t0), b1 = bce_logits(p1, t1);
    float sb  = b0 + b1;
    float sdb = sqrtf(acc0) * b0 + sqrtf(acc1) * b1;

    #pragma unroll
    for (int o = 32; o > 0; o >>= 1) {
        mx  = fmaxf(mx, __shfl_down(mx, o, 64));
        sb  += __shfl_down(sb, o, 64);
        sdb += __shfl_down(sdb, o, 64);
    }
    if (l == 0) { red[0][wv] = mx; red[1][wv] = sb; red[2][wv] = sdb; }
    __syncthreads();
    if (tid == 0) {
        float m2 = red[0][0], s2 = red[1][0], d2 = red[2][0];
        #pragma unroll
        for (int k = 1; k < 16; ++k) {
            m2 = fmaxf(m2, red[0][k]);
            s2 += red[1][k];
            d2 += red[2][k];
        }
        pmx [blockIdx.x] = m2;
        psb [blockIdx.x] = s2;
        psdb[blockIdx.x] = d2;
    }
}

// 256 partials -> scalar. Images are contiguous 32-block runs.
__global__ void final_reduce(const float* __restrict__ pmx, const float* __restrict__ psb,
                             const float* __restrict__ psdb, float* __restrict__ out) {
    const int tid = threadIdx.x;                   // 256 threads
    const int img = tid >> 5, j = tid & 31;        // 8 images x 32 lanes
    const int e = (img << 5) + j;
    float mx = pmx[e], sb = psb[e], sdb = psdb[e];
    #pragma unroll
    for (int o = 16; o > 0; o >>= 1) {             // width-32 groups stay per-image
        mx  = fmaxf(mx, __shfl_down(mx, o, 32));
        sb  += __shfl_down(sb, o, 32);
        sdb += __shfl_down(sdb, o, 32);
    }
    __shared__ float cimg[8], simg[8];
    if (j == 0) {
        cimg[img] = sdb / (sqrtf(mx) + 1e-7f);     // sqrt commutes with max
        simg[img] = sb;
    }
    __syncthreads();
    if (tid == 0) {
        float tot = 0.0f;
        #pragma unroll
        for (int i = 0; i < 8; ++i) tot += simg[i] + cimg[i];
        out[0] = tot * (1.0f / (float)NPIX);
    }
}

extern "C" void kernel_launch(void* const* d_in, const int* in_sizes, int n_in,
                              void* d_out, int out_size, void* d_ws, size_t ws_size,
                              hipStream_t stream) {
    const float* pred   = (const float*)d_in[0];
    const float* target = (const float*)d_in[1];

    float* pmx  = (float*)d_ws;
    float* psb  = pmx + NBLKA;
    float* psdb = psb + NBLKA;

    fused_edt_bce<<<NBLKA, 1024, 0, stream>>>(target, pred, pmx, psb, psdb);
    final_reduce<<<1, 256, 0, stream>>>(pmx, psb, psdb, (float*)d_out);
}